// Round 12
// baseline (140.632 us; speedup 1.0000x reference)
//
#include <hip/hip_runtime.h>
#include <hip/hip_bf16.h>

// Problem constants (B=8,S=24,N=4096,K=9,C1=32,C2=16)
#define NB 8
#define NS 24
#define NN 4096
#define NC1 32
#define NC2 16
#define BN_COUNT 32768.0f

typedef float f32x4 __attribute__((ext_vector_type(4)));
typedef short bf16x8 __attribute__((ext_vector_type(8)));
union U8 { int4 i; bf16x8 b; };
union Q  { uint4 v; unsigned u[4]; };

#define PERM_LO 0x05040100u
#define PERM_HI 0x07060302u
// __builtin_amdgcn_perm(a, b, sel): bytes 0-3 = b, 4-7 = a.
// PERM_LO -> {lo16(b), lo16(a)} ; PERM_HI -> {hi16(b), hi16(a)}

__device__ __forceinline__ unsigned short bfbits(float x) {
    __hip_bfloat16 h = __float2bfloat16(x);
    return *(unsigned short*)&h;
}

// ---------------------------------------------------------------------------
// Kernel 1: layer 1 (proven body) + fused table builder (proven R9).
// ---------------------------------------------------------------------------
__global__ __launch_bounds__(256) void k_l1tab(const float* __restrict__ input,
                                               const float* __restrict__ W1,
                                               const float* __restrict__ b1,
                                               uint4* __restrict__ hp,
                                               const int* __restrict__ neigh,
                                               int* __restrict__ G2M,
                                               int* __restrict__ G3M,
                                               const float* __restrict__ W2,
                                               const float* __restrict__ W3,
                                               __hip_bfloat16* __restrict__ W2B,
                                               __hip_bfloat16* __restrict__ W3B) {
    __shared__ __align__(16) float win[4680];
    __shared__ __align__(16) float corner[72];
    int blk = blockIdx.x;                 // 1868 = 1536 l1 + 332 tables
    if (blk >= 1536) {
        int j = (blk - 1536) * 256 + threadIdx.x;    // < 84992
        if (j < 36864) {                             // G2M
            int j8 = j & 7;
            int tkbl = j >> 3;
            int l = tkbl & 63;
            int tkb = tkbl >> 6;                     // < 72
            int t = tkb / 9, kb = tkb - t * 9;
            int r = t * 16 + (l & 15);
            int k = kb * 32 + ((l >> 4) << 3) + j8;
            int rem = r * 288 + k;
            G2M[j] = neigh[(rem & 4095) * 9 + (rem >> 12)];
        } else if (j < 77824) {                      // G3M (40960)
            int t2 = j - 36864;
            int j8 = t2 & 7;
            int tkbl = t2 >> 3;
            int l = tkbl & 63;
            int tkb = tkbl >> 6;                     // < 80
            int t = tkb / 5, kb = tkb - t * 5;
            int r = t * 16 + (l & 15);
            int k = kb * 32 + ((l >> 4) << 3) + j8;
            int rem = r * 144 + k;
            G3M[t2] = (k < 144) ? neigh[(rem & 4095) * 9 + (rem >> 12)] : 0;
        } else if (j < 82432) {                      // W2B (4608)
            int jj = j - 77824;
            int kb = jj >> 9;
            int rest = jj & 511;
            int l = rest >> 3, j8 = rest & 7;
            int o = l & 15;
            int k = kb * 32 + ((l >> 4) << 3) + j8;
            W2B[jj] = __float2bfloat16(W2[o * 288 + k]);
        } else {                                     // W3B (2560)
            int jj = j - 82432;
            int kb = jj >> 9;
            int rest = jj & 511;
            int l = rest >> 3, j8 = rest & 7;
            int o = l & 15;
            int k = kb * 32 + ((l >> 4) << 3) + j8;
            W3B[jj] = __float2bfloat16((o == 0 && k < 144) ? W3[k] : 0.f);
        }
        return;
    }

    int w = blk & 7, bs = blk >> 3;
    int n0 = w * 512;
    const float* A = input + (size_t)bs * 36864;
    int base = n0 * 9;
    int cnt4 = min(4680, 36864 - base) >> 2;
    const float4* A4 = (const float4*)(A + base);
    float4* win4 = (float4*)win;
    for (int j = threadIdx.x; j < cnt4; j += 256) win4[j] = A4[j];
    if (threadIdx.x < 18) ((float4*)corner)[threadIdx.x] = ((const float4*)A)[threadIdx.x];
    __syncthreads();

    for (int i = threadIdx.x; i < 522; i += 256) {
        int j = i / 58, off = i - j * 58;
        int x = j * 4096 + n0;
        int pstart = (x + 8) / 9;
        int pend   = (x + 520) / 9;
        int p = pstart + off;
        if (p >= pend) continue;
        int nf = (p * 9) & 4095;
        float v[9];
        int wb = (nf - n0) * 9 + j;
        if (nf <= 4087) {
#pragma unroll
            for (int m = 0; m < 9; m++) v[m] = win[wb + 9 * m];
        } else {
            int nw = 4096 - nf;
#pragma unroll
            for (int m = 0; m < 9; m++)
                v[m] = (m < nw) ? win[wb + 9 * m]
                                : corner[(nf + m - 4096) * 9 + j + 1];
        }
        float acc[32];
#pragma unroll 4
        for (int c = 0; c < 32; c++) {
            float a = b1[c];
#pragma unroll
            for (int m = 0; m < 9; m++) a = fmaf(v[m], W1[c * 9 + m], a);
            acc[c] = fmaxf(a, 0.f);
        }
#pragma unroll
        for (int pl = 0; pl < 4; pl++) {
            uint4 d;
            d.x = (unsigned)bfbits(acc[pl * 8 + 0]) | ((unsigned)bfbits(acc[pl * 8 + 1]) << 16);
            d.y = (unsigned)bfbits(acc[pl * 8 + 2]) | ((unsigned)bfbits(acc[pl * 8 + 3]) << 16);
            d.z = (unsigned)bfbits(acc[pl * 8 + 4]) | ((unsigned)bfbits(acc[pl * 8 + 5]) << 16);
            d.w = (unsigned)bfbits(acc[pl * 8 + 6]) | ((unsigned)bfbits(acc[pl * 8 + 7]) << 16);
            hp[((size_t)pl * 192 + bs) * NN + p] = d;
        }
    }
}

// ---------------------------------------------------------------------------
// Kernel 2: layer 2 via MFMA, 512-thread WG per (bs, pl), R11-proven body.
// NEW: y2 stored in the MFMA-natural layout [bs][o][n] bf16 -> each lane
// stores 4 consecutive bf16 (one coalesced 8B uint2) per c instead of 32
// scattered 2B stores. The [n][8ch] transpose moves to l3's staging.
// ---------------------------------------------------------------------------
__global__ __launch_bounds__(512, 4) void k_layer2(const uint4* __restrict__ hp,
                                                   const int4* __restrict__ G2M4,
                                                   const int4* __restrict__ W2B4,
                                                   const float* __restrict__ b2,
                                                   __hip_bfloat16* __restrict__ y2,
                                                   float* __restrict__ psum,
                                                   float* __restrict__ psq) {
    __shared__ __align__(16) uint4 hl[4096];       // 64 KB
    __shared__ float wred[2][8][16];
    int blk = blockIdx.x;                 // 768 = 192 bs * 4 pl
    int pl = blk & 3, bs = blk >> 2;

    int tid = threadIdx.x;
    int l = tid & 63, w = tid >> 6;       // w = r-tile 0..7
    int o = l & 15, q = l >> 4;

    // issue kb=0 index + B-frag loads BEFORE staging so their latency
    // overlaps the 64KB LDS fill
    const int4* gp = G2M4 + (size_t)(w * 9) * 128 + l * 2;
    int4 ia = gp[0];
    int4 ib = gp[1];
    U8 bf; bf.i = W2B4[l];

    const uint4* hb = hp + ((size_t)pl * 192 + bs) * NN;
    for (int j = tid; j < 4096; j += 512) hl[j] = hb[j];
    __syncthreads();

    float bb = b2[o];
    float s1 = 0.f, s2 = 0.f;

    f32x4 acc[8];
#pragma unroll
    for (int c = 0; c < 8; c++) acc[c] = (f32x4){0.f, 0.f, 0.f, 0.f};

#pragma unroll
    for (int kb = 0; kb < 9; kb++) {
        int4 na, nb; U8 nbf;
        if (kb < 8) {                     // prefetch kb+1 (folds at unroll)
            na = gp[(kb + 1) * 128];
            nb = gp[(kb + 1) * 128 + 1];
            nbf.i = W2B4[(kb + 1) * 64 + l];
        }
        Q d[8];
        d[0].v = hl[ia.x]; d[1].v = hl[ia.y]; d[2].v = hl[ia.z]; d[3].v = hl[ia.w];
        d[4].v = hl[ib.x]; d[5].v = hl[ib.y]; d[6].v = hl[ib.z]; d[7].v = hl[ib.w];
#pragma unroll
        for (int c = 0; c < 8; c++) {
            const int q2 = c >> 1;
            const unsigned sel = (c & 1) ? PERM_HI : PERM_LO;
            U8 Af;
            Af.i.x = __builtin_amdgcn_perm(d[1].u[q2], d[0].u[q2], sel);
            Af.i.y = __builtin_amdgcn_perm(d[3].u[q2], d[2].u[q2], sel);
            Af.i.z = __builtin_amdgcn_perm(d[5].u[q2], d[4].u[q2], sel);
            Af.i.w = __builtin_amdgcn_perm(d[7].u[q2], d[6].u[q2], sel);
            acc[c] = __builtin_amdgcn_mfma_f32_16x16x32_bf16(Af.b, bf.b, acc[c], 0, 0, 0);
        }
        if (kb < 8) { ia = na; ib = nb; bf = nbf; }
    }

    // epilogue: coalesced 8B stores into y2[bs][o][n]
    int rbase = w * 16 + q * 4;
    __hip_bfloat16* yb = y2 + ((size_t)bs * NC2 + o) * NN;
#pragma unroll
    for (int c = 0; c < 8; c++) {
        float v0 = acc[c][0] + bb;
        float v1 = acc[c][1] + bb;
        float v2 = acc[c][2] + bb;
        float v3 = acc[c][3] + bb;
        s1 += v0 + v1 + v2 + v3;
        s2 += v0 * v0 + v1 * v1 + v2 * v2 + v3 * v3;
        int n0 = (pl * 8 + c) * 128 + rbase;      // multiple of 4 -> 8B aligned
        uint2 uu;
        uu.x = (unsigned)bfbits(v0) | ((unsigned)bfbits(v1) << 16);
        uu.y = (unsigned)bfbits(v2) | ((unsigned)bfbits(v3) << 16);
        *(uint2*)(yb + n0) = uu;
    }

    s1 += __shfl_xor(s1, 16); s1 += __shfl_xor(s1, 32);
    s2 += __shfl_xor(s2, 16); s2 += __shfl_xor(s2, 32);
    if (l < 16) { wred[0][w][l] = s1; wred[1][w][l] = s2; }
    __syncthreads();
    if (tid < 16) {
        float a = 0.f, b = 0.f;
#pragma unroll
        for (int ww = 0; ww < 8; ww++) { a += wred[0][ww][tid]; b += wred[1][ww][tid]; }
        int srow = (bs % NS) * 16 + tid;
        int col  = (bs / NS) * 4 + pl;    // 32 cols
        psum[srow * 32 + col] = a;
        psq [srow * 32 + col] = b;
    }
}

// ---------------------------------------------------------------------------
// Kernel 3: fused BN-stat + BN + relu + layer 3 (MFMA) + relu, 512-thr WG
// per (bs, oct). Staging now reads y2[bs][o][n] rows (8 coalesced dword
// streams) and transposes to the [n][8ch] LDS layout with the same
// perm/round arithmetic. Gather loop / pipelining / store are R11-proven.
// ---------------------------------------------------------------------------
__global__ __launch_bounds__(512, 4) void k_l3bn(const __hip_bfloat16* __restrict__ y2,
                                                 const int4* __restrict__ G3M4,
                                                 const int4* __restrict__ W3B4,
                                                 const float* __restrict__ psum,
                                                 const float* __restrict__ psq,
                                                 const float* __restrict__ gamma,
                                                 const float* __restrict__ beta,
                                                 const float* __restrict__ b3,
                                                 float* __restrict__ out) {
    __shared__ __align__(16) uint4 zl[4096];       // 64 KB, zl[n] = 8ch of node n
    __shared__ float scl[8], shf[8];
    int blk = blockIdx.x;                 // 384 = 192 bs * 2 oct
    int oct = blk & 1, bs = blk >> 1;
    int s = bs % NS;
    int tid = threadIdx.x;

    if (tid < 256) {   // BN stat reduce: 8 rows x 32 cols, one value/thread
        int jj = tid >> 5, col = tid & 31;
        int row = s * 16 + oct * 8 + jj;
        float sv = psum[row * 32 + col];
        float qv = psq [row * 32 + col];
        for (int off = 16; off; off >>= 1) {
            sv += __shfl_down(sv, off, 32);
            qv += __shfl_down(qv, off, 32);
        }
        if (col == 0) {
            float mean = sv * (1.0f / BN_COUNT);
            float var  = qv * (1.0f / BN_COUNT) - mean * mean;
            float inv  = rsqrtf(var + 1e-5f);
            int o = oct * 8 + jj;
            float scv = gamma[o] * inv;
            scl[jj] = scv;
            shf[jj] = beta[o] - mean * scv;
        }
    }
    __syncthreads();

    float sc[8], sh[8];
#pragma unroll
    for (int jj = 0; jj < 8; jj++) { sc[jj] = scl[jj]; sh[jj] = shf[jj]; }

    int l = tid & 63, w = tid >> 6;       // w = 0..7
    int o = l & 15, q = l >> 4;

    // prefetch tt=0 / kb=0 idx + B-frag before staging
    const int4* gp0 = G3M4 + (size_t)(w * 5) * 128 + l * 2;       // t = w
    int4 ia = gp0[0];
    int4 ib = gp0[1];
    U8 bf; bf.i = W3B4[l];

    // staging with transpose: 8 coalesced dword rows -> zl[n][8ch]
    const unsigned* yrow = (const unsigned*)(y2 + ((size_t)bs * NC2 + oct * 8) * NN);
    for (int j = tid; j < 2048; j += 512) {       // node pair 2j, 2j+1
        unsigned u[8];
#pragma unroll
        for (int jj = 0; jj < 8; jj++) u[jj] = yrow[jj * 2048 + j];
        uint4 pk0, pk1;
        unsigned* p0 = (unsigned*)&pk0;
        unsigned* p1 = (unsigned*)&pk1;
#pragma unroll
        for (int dd = 0; dd < 4; dd++) {
            unsigned ua = u[dd * 2], ub = u[dd * 2 + 1];
            float a_lo = fmaxf(fmaf(__uint_as_float(ua << 16),         sc[dd*2],   sh[dd*2]),   0.f);
            float a_hi = fmaxf(fmaf(__uint_as_float(ua & 0xffff0000u), sc[dd*2],   sh[dd*2]),   0.f);
            float b_lo = fmaxf(fmaf(__uint_as_float(ub << 16),         sc[dd*2+1], sh[dd*2+1]), 0.f);
            float b_hi = fmaxf(fmaf(__uint_as_float(ub & 0xffff0000u), sc[dd*2+1], sh[dd*2+1]), 0.f);
            // round to bf16 (half-up) and pack {ch2dd, ch2dd+1}
            p0[dd] = __builtin_amdgcn_perm(__float_as_uint(b_lo) + 0x8000u,
                                           __float_as_uint(a_lo) + 0x8000u, PERM_HI);
            p1[dd] = __builtin_amdgcn_perm(__float_as_uint(b_hi) + 0x8000u,
                                           __float_as_uint(a_hi) + 0x8000u, PERM_HI);
        }
        zl[2 * j]     = pk0;
        zl[2 * j + 1] = pk1;
    }
    __syncthreads();

    float b3v = b3[0];

#pragma unroll
    for (int tt = 0; tt < 2; tt++) {
        int t = tt * 8 + w;               // r-tile 0..15
        const int4* gp = G3M4 + (size_t)(t * 5) * 128 + l * 2;
        f32x4 acc[8];
#pragma unroll
        for (int c = 0; c < 8; c++) acc[c] = (f32x4){0.f, 0.f, 0.f, 0.f};
#pragma unroll
        for (int kb = 0; kb < 5; kb++) {
            int4 na, nb; U8 nbf;
            if (kb < 4) {                 // prefetch kb+1 within this tile
                na = gp[(kb + 1) * 128];
                nb = gp[(kb + 1) * 128 + 1];
                nbf.i = W3B4[(kb + 1) * 64 + l];
            } else if (tt == 0) {         // prefetch next tile's kb=0
                const int4* gpn = G3M4 + (size_t)((8 + w) * 5) * 128 + l * 2;
                na = gpn[0];
                nb = gpn[1];
                nbf.i = W3B4[l];
            }
            Q d[8];
            d[0].v = zl[ia.x]; d[1].v = zl[ia.y]; d[2].v = zl[ia.z]; d[3].v = zl[ia.w];
            d[4].v = zl[ib.x]; d[5].v = zl[ib.y]; d[6].v = zl[ib.z]; d[7].v = zl[ib.w];
#pragma unroll
            for (int c = 0; c < 8; c++) {
                const int q2 = c >> 1;
                const unsigned sel = (c & 1) ? PERM_HI : PERM_LO;
                U8 Af;
                Af.i.x = __builtin_amdgcn_perm(d[1].u[q2], d[0].u[q2], sel);
                Af.i.y = __builtin_amdgcn_perm(d[3].u[q2], d[2].u[q2], sel);
                Af.i.z = __builtin_amdgcn_perm(d[5].u[q2], d[4].u[q2], sel);
                Af.i.w = __builtin_amdgcn_perm(d[7].u[q2], d[6].u[q2], sel);
                acc[c] = __builtin_amdgcn_mfma_f32_16x16x32_bf16(Af.b, bf.b, acc[c], 0, 0, 0);
            }
            if (kb < 4 || tt == 0) { ia = na; ib = nb; bf = nbf; }
        }
        if (o == 0) {                     // C col 0 holds the result
            int rbase = t * 16 + q * 4;
            float* ob = out + (size_t)bs * NN + oct * 2048;
#pragma unroll
            for (int c = 0; c < 8; c++)
#pragma unroll
                for (int i = 0; i < 4; i++)
                    ob[c * 256 + rbase + i] = fmaxf(acc[c][i] + b3v, 0.f);
        }
    }
}

// ---------------------------------------------------------------------------
extern "C" void kernel_launch(void* const* d_in, const int* in_sizes, int n_in,
                              void* d_out, int out_size, void* d_ws, size_t ws_size,
                              hipStream_t stream) {
    const float* input = (const float*)d_in[0];
    const int*   neigh = (const int*)d_in[1];
    const float* W1    = (const float*)d_in[2];
    const float* b1    = (const float*)d_in[3];
    const float* W2    = (const float*)d_in[4];
    const float* b2    = (const float*)d_in[5];
    const float* gamma = (const float*)d_in[6];
    const float* beta  = (const float*)d_in[7];
    const float* W3    = (const float*)d_in[8];
    const float* b3    = (const float*)d_in[9];
    float* out = (float*)d_out;

    // Workspace layout (bytes), all 16B-aligned
    char* ws = (char*)d_ws;
    int*            G2M   = (int*)            (ws);             // 147456
    int*            G3M   = (int*)            (ws + 147456);    // 163840
    __hip_bfloat16* W2B   = (__hip_bfloat16*) (ws + 311296);    // 9216
    __hip_bfloat16* W3B   = (__hip_bfloat16*) (ws + 320512);    // 5120
    uint4*          h     = (uint4*)          (ws + 325632);    // 50331648
    __hip_bfloat16* y2    = (__hip_bfloat16*) (ws + 50657280);  // 25165824
    float*          psum  = (float*)          (ws + 75823104);  // 49152
    float*          psq   = (float*)          (ws + 75872256);  // 49152

    k_l1tab<<<1868, 256, 0, stream>>>(input, W1, b1, h,
                                      neigh, G2M, G3M, W2, W3, W2B, W3B);
    k_layer2<<<768, 512, 0, stream>>>(h, (const int4*)G2M, (const int4*)W2B,
                                      b2, y2, psum, psq);
    k_l3bn<<<384, 512, 0, stream>>>(y2, (const int4*)G3M,
                                    (const int4*)W3B, psum, psq,
                                    gamma, beta, b3, out);
}

// Round 13
// 140.427 us; speedup vs baseline: 1.0015x; 1.0015x over previous
//
#include <hip/hip_runtime.h>
#include <hip/hip_bf16.h>

// Problem constants (B=8,S=24,N=4096,K=9,C1=32,C2=16)
#define NB 8
#define NS 24
#define NN 4096
#define NC1 32
#define NC2 16
#define BN_COUNT 32768.0f

typedef float f32x4 __attribute__((ext_vector_type(4)));
typedef short bf16x8 __attribute__((ext_vector_type(8)));
union U8 { int4 i; bf16x8 b; };
union Q  { uint4 v; unsigned u[4]; };

#define PERM_LO 0x05040100u
#define PERM_HI 0x07060302u
// __builtin_amdgcn_perm(a, b, sel): bytes 0-3 = b, 4-7 = a.
// PERM_LO -> {lo16(b), lo16(a)} ; PERM_HI -> {hi16(b), hi16(a)}

__device__ __forceinline__ unsigned short bfbits(float x) {
    __hip_bfloat16 h = __float2bfloat16(x);
    return *(unsigned short*)&h;
}

// ---------------------------------------------------------------------------
// Kernel 1: layer 1 (proven body) + fused table builder (proven R9).
// ---------------------------------------------------------------------------
__global__ __launch_bounds__(256) void k_l1tab(const float* __restrict__ input,
                                               const float* __restrict__ W1,
                                               const float* __restrict__ b1,
                                               uint4* __restrict__ hp,
                                               const int* __restrict__ neigh,
                                               int* __restrict__ G2M,
                                               int* __restrict__ G3M,
                                               const float* __restrict__ W2,
                                               const float* __restrict__ W3,
                                               __hip_bfloat16* __restrict__ W2B,
                                               __hip_bfloat16* __restrict__ W3B) {
    __shared__ __align__(16) float win[4680];
    __shared__ __align__(16) float corner[72];
    int blk = blockIdx.x;                 // 1868 = 1536 l1 + 332 tables
    if (blk >= 1536) {
        int j = (blk - 1536) * 256 + threadIdx.x;    // < 84992
        if (j < 36864) {                             // G2M
            int j8 = j & 7;
            int tkbl = j >> 3;
            int l = tkbl & 63;
            int tkb = tkbl >> 6;                     // < 72
            int t = tkb / 9, kb = tkb - t * 9;
            int r = t * 16 + (l & 15);
            int k = kb * 32 + ((l >> 4) << 3) + j8;
            int rem = r * 288 + k;
            G2M[j] = neigh[(rem & 4095) * 9 + (rem >> 12)];
        } else if (j < 77824) {                      // G3M (40960)
            int t2 = j - 36864;
            int j8 = t2 & 7;
            int tkbl = t2 >> 3;
            int l = tkbl & 63;
            int tkb = tkbl >> 6;                     // < 80
            int t = tkb / 5, kb = tkb - t * 5;
            int r = t * 16 + (l & 15);
            int k = kb * 32 + ((l >> 4) << 3) + j8;
            int rem = r * 144 + k;
            G3M[t2] = (k < 144) ? neigh[(rem & 4095) * 9 + (rem >> 12)] : 0;
        } else if (j < 82432) {                      // W2B (4608)
            int jj = j - 77824;
            int kb = jj >> 9;
            int rest = jj & 511;
            int l = rest >> 3, j8 = rest & 7;
            int o = l & 15;
            int k = kb * 32 + ((l >> 4) << 3) + j8;
            W2B[jj] = __float2bfloat16(W2[o * 288 + k]);
        } else {                                     // W3B (2560)
            int jj = j - 82432;
            int kb = jj >> 9;
            int rest = jj & 511;
            int l = rest >> 3, j8 = rest & 7;
            int o = l & 15;
            int k = kb * 32 + ((l >> 4) << 3) + j8;
            W3B[jj] = __float2bfloat16((o == 0 && k < 144) ? W3[k] : 0.f);
        }
        return;
    }

    int w = blk & 7, bs = blk >> 3;
    int n0 = w * 512;
    const float* A = input + (size_t)bs * 36864;
    int base = n0 * 9;
    int cnt4 = min(4680, 36864 - base) >> 2;
    const float4* A4 = (const float4*)(A + base);
    float4* win4 = (float4*)win;
    for (int j = threadIdx.x; j < cnt4; j += 256) win4[j] = A4[j];
    if (threadIdx.x < 18) ((float4*)corner)[threadIdx.x] = ((const float4*)A)[threadIdx.x];
    __syncthreads();

    for (int i = threadIdx.x; i < 522; i += 256) {
        int j = i / 58, off = i - j * 58;
        int x = j * 4096 + n0;
        int pstart = (x + 8) / 9;
        int pend   = (x + 520) / 9;
        int p = pstart + off;
        if (p >= pend) continue;
        int nf = (p * 9) & 4095;
        float v[9];
        int wb = (nf - n0) * 9 + j;
        if (nf <= 4087) {
#pragma unroll
            for (int m = 0; m < 9; m++) v[m] = win[wb + 9 * m];
        } else {
            int nw = 4096 - nf;
#pragma unroll
            for (int m = 0; m < 9; m++)
                v[m] = (m < nw) ? win[wb + 9 * m]
                                : corner[(nf + m - 4096) * 9 + j + 1];
        }
        float acc[32];
#pragma unroll 4
        for (int c = 0; c < 32; c++) {
            float a = b1[c];
#pragma unroll
            for (int m = 0; m < 9; m++) a = fmaf(v[m], W1[c * 9 + m], a);
            acc[c] = fmaxf(a, 0.f);
        }
#pragma unroll
        for (int pl = 0; pl < 4; pl++) {
            uint4 d;
            d.x = (unsigned)bfbits(acc[pl * 8 + 0]) | ((unsigned)bfbits(acc[pl * 8 + 1]) << 16);
            d.y = (unsigned)bfbits(acc[pl * 8 + 2]) | ((unsigned)bfbits(acc[pl * 8 + 3]) << 16);
            d.z = (unsigned)bfbits(acc[pl * 8 + 4]) | ((unsigned)bfbits(acc[pl * 8 + 5]) << 16);
            d.w = (unsigned)bfbits(acc[pl * 8 + 6]) | ((unsigned)bfbits(acc[pl * 8 + 7]) << 16);
            hp[((size_t)pl * 192 + bs) * NN + p] = d;
        }
    }
}

// ---------------------------------------------------------------------------
// Kernel 2: layer 2 via MFMA, 512-thread WG per (bs, pl), R10-proven body +
// software pipelining: kb=0 idx/B-frag loads issued BEFORE the staging
// barrier (overlap global latency with LDS fill); in-loop rotation prefetches
// kb+1 while kb computes.
// ---------------------------------------------------------------------------
__global__ __launch_bounds__(512, 4) void k_layer2(const uint4* __restrict__ hp,
                                                   const int4* __restrict__ G2M4,
                                                   const int4* __restrict__ W2B4,
                                                   const float* __restrict__ b2,
                                                   __hip_bfloat16* __restrict__ y2p,
                                                   float* __restrict__ psum,
                                                   float* __restrict__ psq) {
    __shared__ __align__(16) uint4 hl[4096];       // 64 KB
    __shared__ float wred[2][8][16];
    int blk = blockIdx.x;                 // 768 = 192 bs * 4 pl
    int pl = blk & 3, bs = blk >> 2;

    int tid = threadIdx.x;
    int l = tid & 63, w = tid >> 6;       // w = r-tile 0..7
    int o = l & 15, q = l >> 4;

    // issue kb=0 index + B-frag loads BEFORE staging so their latency
    // overlaps the 64KB LDS fill
    const int4* gp = G2M4 + (size_t)(w * 9) * 128 + l * 2;
    int4 ia = gp[0];
    int4 ib = gp[1];
    U8 bf; bf.i = W2B4[l];

    const uint4* hb = hp + ((size_t)pl * 192 + bs) * NN;
    for (int j = tid; j < 4096; j += 512) hl[j] = hb[j];
    __syncthreads();

    float bb = b2[o];
    float s1 = 0.f, s2 = 0.f;
    __hip_bfloat16* ypl = y2p + (((size_t)(o >> 3) * 192 + bs) * NN) * 8 + (o & 7);

    f32x4 acc[8];
#pragma unroll
    for (int c = 0; c < 8; c++) acc[c] = (f32x4){0.f, 0.f, 0.f, 0.f};

#pragma unroll
    for (int kb = 0; kb < 9; kb++) {
        int4 na, nb; U8 nbf;
        if (kb < 8) {                     // prefetch kb+1 (folds at unroll)
            na = gp[(kb + 1) * 128];
            nb = gp[(kb + 1) * 128 + 1];
            nbf.i = W2B4[(kb + 1) * 64 + l];
        }
        Q d[8];
        d[0].v = hl[ia.x]; d[1].v = hl[ia.y]; d[2].v = hl[ia.z]; d[3].v = hl[ia.w];
        d[4].v = hl[ib.x]; d[5].v = hl[ib.y]; d[6].v = hl[ib.z]; d[7].v = hl[ib.w];
#pragma unroll
        for (int c = 0; c < 8; c++) {
            const int q2 = c >> 1;
            const unsigned sel = (c & 1) ? PERM_HI : PERM_LO;
            U8 Af;
            Af.i.x = __builtin_amdgcn_perm(d[1].u[q2], d[0].u[q2], sel);
            Af.i.y = __builtin_amdgcn_perm(d[3].u[q2], d[2].u[q2], sel);
            Af.i.z = __builtin_amdgcn_perm(d[5].u[q2], d[4].u[q2], sel);
            Af.i.w = __builtin_amdgcn_perm(d[7].u[q2], d[6].u[q2], sel);
            acc[c] = __builtin_amdgcn_mfma_f32_16x16x32_bf16(Af.b, bf.b, acc[c], 0, 0, 0);
        }
        if (kb < 8) { ia = na; ib = nb; bf = nbf; }
    }

    // proven epilogue: scattered bf16 stores into y2 octet planes
    int rbase = w * 16 + q * 4;
#pragma unroll
    for (int c = 0; c < 8; c++) {
        int C = pl * 8 + c;               // layer-2 input channel -> n-block
#pragma unroll
        for (int i = 0; i < 4; i++) {
            float v = acc[c][i] + bb;
            s1 += v; s2 += v * v;
            int n = C * 128 + rbase + i;
            ypl[(size_t)n * 8] = __float2bfloat16(v);
        }
    }

    s1 += __shfl_xor(s1, 16); s1 += __shfl_xor(s1, 32);
    s2 += __shfl_xor(s2, 16); s2 += __shfl_xor(s2, 32);
    if (l < 16) { wred[0][w][l] = s1; wred[1][w][l] = s2; }
    __syncthreads();
    if (tid < 16) {
        float a = 0.f, b = 0.f;
#pragma unroll
        for (int ww = 0; ww < 8; ww++) { a += wred[0][ww][tid]; b += wred[1][ww][tid]; }
        int srow = (bs % NS) * 16 + tid;
        int col  = (bs / NS) * 4 + pl;    // 32 cols
        psum[srow * 32 + col] = a;
        psq [srow * 32 + col] = b;
    }
}

// ---------------------------------------------------------------------------
// Kernel 3: fused BN-stat + BN + relu + layer 3 (MFMA) + relu, 512-thr WG
// per (bs, oct), R10-proven body + the same software pipelining.
// ---------------------------------------------------------------------------
__global__ __launch_bounds__(512, 4) void k_l3bn(const uint4* __restrict__ y2p,
                                                 const int4* __restrict__ G3M4,
                                                 const int4* __restrict__ W3B4,
                                                 const float* __restrict__ psum,
                                                 const float* __restrict__ psq,
                                                 const float* __restrict__ gamma,
                                                 const float* __restrict__ beta,
                                                 const float* __restrict__ b3,
                                                 float* __restrict__ out) {
    __shared__ __align__(16) uint4 zl[4096];       // 64 KB
    __shared__ float scl[8], shf[8];
    int blk = blockIdx.x;                 // 384 = 192 bs * 2 oct
    int oct = blk & 1, bs = blk >> 1;
    int s = bs % NS;
    int tid = threadIdx.x;

    if (tid < 256) {   // BN stat reduce: 8 rows x 32 cols, one value/thread
        int jj = tid >> 5, col = tid & 31;
        int row = s * 16 + oct * 8 + jj;
        float sv = psum[row * 32 + col];
        float qv = psq [row * 32 + col];
        for (int off = 16; off; off >>= 1) {
            sv += __shfl_down(sv, off, 32);
            qv += __shfl_down(qv, off, 32);
        }
        if (col == 0) {
            float mean = sv * (1.0f / BN_COUNT);
            float var  = qv * (1.0f / BN_COUNT) - mean * mean;
            float inv  = rsqrtf(var + 1e-5f);
            int o = oct * 8 + jj;
            float scv = gamma[o] * inv;
            scl[jj] = scv;
            shf[jj] = beta[o] - mean * scv;
        }
    }
    __syncthreads();

    float sc[8], sh[8];
#pragma unroll
    for (int jj = 0; jj < 8; jj++) { sc[jj] = scl[jj]; sh[jj] = shf[jj]; }

    int l = tid & 63, w = tid >> 6;       // w = 0..7
    int o = l & 15, q = l >> 4;

    // prefetch tt=0 / kb=0 idx + B-frag before staging
    const int4* gp0 = G3M4 + (size_t)(w * 5) * 128 + l * 2;       // t = w
    int4 ia = gp0[0];
    int4 ib = gp0[1];
    U8 bf; bf.i = W3B4[l];

    const uint4* yb = y2p + ((size_t)oct * 192 + bs) * NN;
    for (int j = tid; j < 4096; j += 512) {
        uint4 u = yb[j];
        unsigned r[4] = {u.x, u.y, u.z, u.w};
        uint4 pk;
        unsigned* pp = (unsigned*)&pk;
#pragma unroll
        for (int dd = 0; dd < 4; dd++) {
            float lo = fmaxf(fmaf(__uint_as_float(r[dd] << 16),         sc[dd*2],   sh[dd*2]),   0.f);
            float hi = fmaxf(fmaf(__uint_as_float(r[dd] & 0xffff0000u), sc[dd*2+1], sh[dd*2+1]), 0.f);
            unsigned ulo = __float_as_uint(lo) + 0x8000u;   // round to bf16
            unsigned uhi = __float_as_uint(hi) + 0x8000u;
            pp[dd] = __builtin_amdgcn_perm(uhi, ulo, PERM_HI);
        }
        zl[j] = pk;
    }
    __syncthreads();

    float b3v = b3[0];

#pragma unroll
    for (int tt = 0; tt < 2; tt++) {
        int t = tt * 8 + w;               // r-tile 0..15
        const int4* gp = G3M4 + (size_t)(t * 5) * 128 + l * 2;
        f32x4 acc[8];
#pragma unroll
        for (int c = 0; c < 8; c++) acc[c] = (f32x4){0.f, 0.f, 0.f, 0.f};
#pragma unroll
        for (int kb = 0; kb < 5; kb++) {
            int4 na, nb; U8 nbf;
            if (kb < 4) {                 // prefetch kb+1 within this tile
                na = gp[(kb + 1) * 128];
                nb = gp[(kb + 1) * 128 + 1];
                nbf.i = W3B4[(kb + 1) * 64 + l];
            } else if (tt == 0) {         // prefetch next tile's kb=0
                const int4* gpn = G3M4 + (size_t)((8 + w) * 5) * 128 + l * 2;
                na = gpn[0];
                nb = gpn[1];
                nbf.i = W3B4[l];
            }
            Q d[8];
            d[0].v = zl[ia.x]; d[1].v = zl[ia.y]; d[2].v = zl[ia.z]; d[3].v = zl[ia.w];
            d[4].v = zl[ib.x]; d[5].v = zl[ib.y]; d[6].v = zl[ib.z]; d[7].v = zl[ib.w];
#pragma unroll
            for (int c = 0; c < 8; c++) {
                const int q2 = c >> 1;
                const unsigned sel = (c & 1) ? PERM_HI : PERM_LO;
                U8 Af;
                Af.i.x = __builtin_amdgcn_perm(d[1].u[q2], d[0].u[q2], sel);
                Af.i.y = __builtin_amdgcn_perm(d[3].u[q2], d[2].u[q2], sel);
                Af.i.z = __builtin_amdgcn_perm(d[5].u[q2], d[4].u[q2], sel);
                Af.i.w = __builtin_amdgcn_perm(d[7].u[q2], d[6].u[q2], sel);
                acc[c] = __builtin_amdgcn_mfma_f32_16x16x32_bf16(Af.b, bf.b, acc[c], 0, 0, 0);
            }
            if (kb < 4 || tt == 0) { ia = na; ib = nb; bf = nbf; }
        }
        if (o == 0) {                     // C col 0 holds the result
            int rbase = t * 16 + q * 4;
            float* ob = out + (size_t)bs * NN + oct * 2048;
#pragma unroll
            for (int c = 0; c < 8; c++)
#pragma unroll
                for (int i = 0; i < 4; i++)
                    ob[c * 256 + rbase + i] = fmaxf(acc[c][i] + b3v, 0.f);
        }
    }
}

// ---------------------------------------------------------------------------
extern "C" void kernel_launch(void* const* d_in, const int* in_sizes, int n_in,
                              void* d_out, int out_size, void* d_ws, size_t ws_size,
                              hipStream_t stream) {
    const float* input = (const float*)d_in[0];
    const int*   neigh = (const int*)d_in[1];
    const float* W1    = (const float*)d_in[2];
    const float* b1    = (const float*)d_in[3];
    const float* W2    = (const float*)d_in[4];
    const float* b2    = (const float*)d_in[5];
    const float* gamma = (const float*)d_in[6];
    const float* beta  = (const float*)d_in[7];
    const float* W3    = (const float*)d_in[8];
    const float* b3    = (const float*)d_in[9];
    float* out = (float*)d_out;

    // Workspace layout (bytes), all 16B-aligned
    char* ws = (char*)d_ws;
    int*            G2M   = (int*)            (ws);             // 147456
    int*            G3M   = (int*)            (ws + 147456);    // 163840
    __hip_bfloat16* W2B   = (__hip_bfloat16*) (ws + 311296);    // 9216
    __hip_bfloat16* W3B   = (__hip_bfloat16*) (ws + 320512);    // 5120
    uint4*          h     = (uint4*)          (ws + 325632);    // 50331648
    __hip_bfloat16* y2    = (__hip_bfloat16*) (ws + 50657280);  // 25165824
    float*          psum  = (float*)          (ws + 75823104);  // 49152
    float*          psq   = (float*)          (ws + 75872256);  // 49152

    k_l1tab<<<1868, 256, 0, stream>>>(input, W1, b1, h,
                                      neigh, G2M, G3M, W2, W3, W2B, W3B);
    k_layer2<<<768, 512, 0, stream>>>(h, (const int4*)G2M, (const int4*)W2B,
                                      b2, y2, psum, psq);
    k_l3bn<<<384, 512, 0, stream>>>((const uint4*)y2, (const int4*)G3M,
                                    (const int4*)W3B, psum, psq,
                                    gamma, beta, b3, out);
}